// Round 13
// baseline (169.936 us; speedup 1.0000x reference)
//
#include <hip/hip_runtime.h>
#include <hip/hip_bf16.h>
#include <stdint.h>

typedef __attribute__((ext_vector_type(8))) short short8;
typedef __attribute__((ext_vector_type(4))) float f32x4;

#define DDIM 128

__device__ __forceinline__ unsigned short f2bf(float f) {
  union { float f; unsigned u; } v; v.f = f;
  unsigned u = v.u + 0x7FFFu + ((v.u >> 16) & 1u);  // RNE
  return (unsigned short)(u >> 16);
}
__device__ __forceinline__ float bf2f(unsigned short b) {
  union { unsigned u; float f; } v; v.u = ((unsigned)b) << 16;
  return v.f;
}
// packed f32 pair -> 2x bf16 in one u32 (v_cvt_pk_bf16_f32, RNE)
__device__ __forceinline__ unsigned pack2(float lo, float hi) {
  __hip_bfloat162 h2 = __float22bfloat162_rn(make_float2(lo, hi));
  unsigned u; __builtin_memcpy(&u, &h2, 4); return u;
}
__device__ __forceinline__ short8 pack8f(float4 a, float4 b) {
  union { unsigned u[4]; short8 s; } r;
  r.u[0] = pack2(a.x, a.y); r.u[1] = pack2(a.z, a.w);
  r.u[2] = pack2(b.x, b.y); r.u[3] = pack2(b.z, b.w);
  return r.s;
}

// ---- weights fp32 -> bf16 staging: wb = [W1 rows; W2 rows] = [256][128]
__global__ void convW(const float* __restrict__ W1, const float* __restrict__ W2,
                      unsigned short* __restrict__ wb) {
  int i = blockIdx.x * blockDim.x + threadIdx.x;
  if (i < 16384)      wb[i] = f2bf(W1[i]);
  else if (i < 32768) wb[i] = f2bf(W2[i - 16384]);
}

// ---- proj v6: LDS-FREE. B-fragment = 8 contiguous x f32 elements per lane
//      loaded directly from global (2x float4 + 4 cvt_pk), no barriers.
//      D[c][r] layout (swapped operands) -> packed 8B stores.
__global__ __launch_bounds__(256) void proj(
    const float* __restrict__ xu, int NUr, int gU,
    const float* __restrict__ xi, int NIr, int nTiles,
    const unsigned short* __restrict__ wb,
    const float* __restrict__ b1, const float* __restrict__ b2,
    unsigned short* __restrict__ Au, unsigned short* __restrict__ Qu,
    unsigned short* __restrict__ Ai, unsigned short* __restrict__ Qi) {
  const int lane  = threadIdx.x & 63;
  const int wv    = threadIdx.x >> 6;
  const int col16 = lane & 15;
  const int kgrp  = lane >> 4;

  // W fragments once per block (A-operand)
  short8 wf[2][2][4];
#pragma unroll
  for (int m = 0; m < 2; ++m)
#pragma unroll
    for (int ct = 0; ct < 2; ++ct) {
      const int c = m * 128 + wv * 32 + ct * 16 + col16;
#pragma unroll
      for (int ks = 0; ks < 4; ++ks)
        wf[m][ct][ks] = *(const short8*)(wb + (size_t)c * DDIM + ks * 32 + kgrp * 8);
    }
  // bias for the 4 consecutive cols this thread owns per ct
  float4 bc12[2];
#pragma unroll
  for (int ct = 0; ct < 2; ++ct) {
    const int cb = wv * 32 + ct * 16 + kgrp * 4;
    float4 v1 = *(const float4*)(b1 + cb);
    float4 v2 = *(const float4*)(b2 + cb);
    bc12[ct] = make_float4(v1.x + v2.x, v1.y + v2.y, v1.z + v2.z, v1.w + v2.w);
  }

  for (int t = blockIdx.x; t < nTiles; t += gridDim.x) {
    const bool isU = (t < gU);
    const float* __restrict__ x = isU ? xu : xi;
    const int nrows = isU ? NUr : NIr;
    const int tt    = isU ? t : (t - gU);
    unsigned short* __restrict__ Aout = isU ? Au : Ai;
    unsigned short* __restrict__ Qout = isU ? Qu : Qi;
    const int r0 = tt * 64;
    const bool full = (r0 + 64 <= nrows);

    f32x4 acc[4][2][2];
#pragma unroll
    for (int rt = 0; rt < 4; ++rt)
#pragma unroll
      for (int m = 0; m < 2; ++m)
#pragma unroll
        for (int ct = 0; ct < 2; ++ct)
          acc[rt][m][ct] = (f32x4){0.f, 0.f, 0.f, 0.f};

    if (full) {
#pragma unroll
      for (int ks = 0; ks < 4; ++ks)
#pragma unroll
        for (int rt = 0; rt < 4; ++rt) {
          const float* xp = x + (size_t)(r0 + rt * 16 + col16) * DDIM + ks * 32 + kgrp * 8;
          short8 a = pack8f(*(const float4*)xp, *(const float4*)(xp + 4));
#pragma unroll
          for (int m = 0; m < 2; ++m)
#pragma unroll
            for (int ct = 0; ct < 2; ++ct)
              acc[rt][m][ct] = __builtin_amdgcn_mfma_f32_16x16x32_bf16(wf[m][ct][ks], a, acc[rt][m][ct], 0, 0, 0);
        }
    } else {
#pragma unroll
      for (int ks = 0; ks < 4; ++ks)
#pragma unroll
        for (int rt = 0; rt < 4; ++rt) {
          const int r = r0 + rt * 16 + col16;
          float4 xa = make_float4(0.f, 0.f, 0.f, 0.f), xb = xa;
          if (r < nrows) {
            const float* xp = x + (size_t)r * DDIM + ks * 32 + kgrp * 8;
            xa = *(const float4*)xp;
            xb = *(const float4*)(xp + 4);
          }
          short8 a = pack8f(xa, xb);
#pragma unroll
          for (int m = 0; m < 2; ++m)
#pragma unroll
            for (int ct = 0; ct < 2; ++ct)
              acc[rt][m][ct] = __builtin_amdgcn_mfma_f32_16x16x32_bf16(wf[m][ct][ks], a, acc[rt][m][ct], 0, 0, 0);
        }
    }

    // epilogue: thread owns row r, cols cb..cb+3 per ct -> 8B packed stores
#pragma unroll
    for (int rt = 0; rt < 4; ++rt) {
      const int r = r0 + rt * 16 + col16;
      if (full || r < nrows) {
#pragma unroll
        for (int ct = 0; ct < 2; ++ct) {
          const int cb = wv * 32 + ct * 16 + kgrp * 4;
          const f32x4 y1 = acc[rt][0][ct];
          const f32x4 y2 = acc[rt][1][ct];
          uint2 ap, qp;
          ap.x = pack2(y1[0] + y2[0] + bc12[ct].x, y1[1] + y2[1] + bc12[ct].y);
          ap.y = pack2(y1[2] + y2[2] + bc12[ct].z, y1[3] + y2[3] + bc12[ct].w);
          qp.x = pack2(y2[0], y2[1]);
          qp.y = pack2(y2[2], y2[3]);
          *(uint2*)(Aout + (size_t)r * DDIM + cb) = ap;
          *(uint2*)(Qout + (size_t)r * DDIM + cb) = qp;
        }
      }
    }
  }
}

// ---- hist: rank[i] = per-dst arrival index; ONE atomic per edge.
__global__ void hist(const int* __restrict__ dst_ui, int nE_ui,
                     const int* __restrict__ dst_iu, int nE_iu,
                     int NU, int* __restrict__ deg, int* __restrict__ rank) {
  int i = blockIdx.x * blockDim.x + threadIdx.x;
  const int stride = gridDim.x * blockDim.x;
  const int nTot = nE_ui + nE_iu;
  for (; i < nTot; i += stride) {
    const int d = (i < nE_ui) ? (NU + dst_ui[i]) : dst_iu[i - nE_ui];
    rank[i] = atomicAdd(&deg[d], 1);
  }
}

__global__ __launch_bounds__(1024) void scan1(const int* __restrict__ deg, int n,
                                              int* __restrict__ exsc, int* __restrict__ bsum) {
  __shared__ int wsum[16];
  const int tid = threadIdx.x;
  const int g = blockIdx.x * 1024 + tid;
  const int lane = tid & 63, wv = tid >> 6;
  int v = (g < n) ? deg[g] : 0;
  int x = v;
#pragma unroll
  for (int off = 1; off < 64; off <<= 1) {
    int y = __shfl_up(x, off);
    if (lane >= off) x += y;
  }
  if (lane == 63) wsum[wv] = x;
  __syncthreads();
  if (wv == 0 && lane < 16) {
    int s = wsum[lane];
#pragma unroll
    for (int off = 1; off < 16; off <<= 1) {
      int y = __shfl_up(s, off);
      if (lane >= off) s += y;
    }
    wsum[lane] = s;
  }
  __syncthreads();
  int woff = (wv == 0) ? 0 : wsum[wv - 1];
  int inc = x + woff;
  if (g < n) exsc[g] = inc - v;
  if (tid == 1023) bsum[blockIdx.x] = inc;
}

__global__ __launch_bounds__(256) void scan2(int* __restrict__ bsum, int nb) {
  __shared__ int tmp[256];
  const int tid = threadIdx.x;
  int v = (tid < nb) ? bsum[tid] : 0;
  int x = v;
  tmp[tid] = v;
  __syncthreads();
#pragma unroll
  for (int off = 1; off < 256; off <<= 1) {
    int y = (tid >= off) ? tmp[tid - off] : 0;
    __syncthreads();
    x += y;
    tmp[tid] = x;
    __syncthreads();
  }
  if (tid < nb) bsum[tid] = x - v;
}

__global__ void scan3(const int* __restrict__ exsc, const int* __restrict__ bsum,
                      int n, int nETot, int* __restrict__ rowptr) {
  int g = blockIdx.x * blockDim.x + threadIdx.x;
  if (g < n) rowptr[g] = exsc[g] + bsum[g >> 10];
  if (g == n) rowptr[n] = nETot;
}

// ---- fillcsr: ATOMIC-FREE — pos = rowptr[dst] + rank[i]
__global__ void fillcsr(const int* __restrict__ src_ui, const int* __restrict__ dst_ui,
                        const float* __restrict__ nrm_ui, int nE_ui,
                        const int* __restrict__ src_iu, const int* __restrict__ dst_iu,
                        const float* __restrict__ nrm_iu, int nE_iu,
                        int NU, const int* __restrict__ rowptr,
                        const int* __restrict__ rank, int2* __restrict__ pay) {
  int i = blockIdx.x * blockDim.x + threadIdx.x;
  int stride = gridDim.x * blockDim.x;
  int nTot = nE_ui + nE_iu;
  for (; i < nTot; i += stride) {
    int d, s; float nm;
    if (i < nE_ui) { d = NU + dst_ui[i]; s = src_ui[i]; nm = nrm_ui[i]; }
    else { int k = i - nE_ui; d = dst_iu[k]; s = src_iu[k]; nm = nrm_iu[k]; }
    const int pos = rowptr[d] + rank[i];
    int2 p; p.x = s; p.y = __float_as_int(nm);
    pay[pos] = p;
  }
}

// ---- pullfin v3: S computed inline from payload norms.
// h[r] = A_self[r] + (S-1)*Q[r] - b2 + sum_e norm_e * A_gather[src_e]; lrelu+L2norm.
__global__ __launch_bounds__(256) void pullfin(
    const int* __restrict__ rowptr, const int2* __restrict__ pay,
    const unsigned short* __restrict__ Ac,
    const unsigned short* __restrict__ Au, const unsigned short* __restrict__ Ai,
    const unsigned short* __restrict__ Qc,
    const float* __restrict__ b2,
    float* __restrict__ out, int NU, int ntot) {
  const int lane = threadIdx.x & 63;
  const int h    = lane & 31;
  const int half = lane >> 5;
  float b2v[4];
#pragma unroll
  for (int j = 0; j < 4; ++j) b2v[j] = b2[h * 4 + j];

  int r = (((blockIdx.x * blockDim.x + threadIdx.x) >> 6) << 1) + half;
  const int rstride = ((gridDim.x * blockDim.x) >> 6) << 1;
  for (; r < ntot; r += rstride) {
    const unsigned short* Ag = (r < NU) ? Ai : Au;
    const int beg = rowptr[r], end = rowptr[r + 1];
    float a0 = 0.f, a1 = 0.f, a2 = 0.f, a3 = 0.f, sn = 0.f;
    int e = beg;
    for (; e + 3 < end; e += 4) {
      int2 p0 = pay[e], p1 = pay[e + 1], p2 = pay[e + 2], p3 = pay[e + 3];
      uint2 g0 = *(const uint2*)(Ag + (size_t)p0.x * DDIM + h * 4);
      uint2 g1 = *(const uint2*)(Ag + (size_t)p1.x * DDIM + h * 4);
      uint2 g2 = *(const uint2*)(Ag + (size_t)p2.x * DDIM + h * 4);
      uint2 g3 = *(const uint2*)(Ag + (size_t)p3.x * DDIM + h * 4);
      float n0 = __int_as_float(p0.y), n1 = __int_as_float(p1.y);
      float n2 = __int_as_float(p2.y), n3 = __int_as_float(p3.y);
      sn += (n0 + n1) + (n2 + n3);
      a0 += n0 * bf2f((unsigned short)(g0.x & 0xffffu));
      a1 += n0 * bf2f((unsigned short)(g0.x >> 16));
      a2 += n0 * bf2f((unsigned short)(g0.y & 0xffffu));
      a3 += n0 * bf2f((unsigned short)(g0.y >> 16));
      a0 += n1 * bf2f((unsigned short)(g1.x & 0xffffu));
      a1 += n1 * bf2f((unsigned short)(g1.x >> 16));
      a2 += n1 * bf2f((unsigned short)(g1.y & 0xffffu));
      a3 += n1 * bf2f((unsigned short)(g1.y >> 16));
      a0 += n2 * bf2f((unsigned short)(g2.x & 0xffffu));
      a1 += n2 * bf2f((unsigned short)(g2.x >> 16));
      a2 += n2 * bf2f((unsigned short)(g2.y & 0xffffu));
      a3 += n2 * bf2f((unsigned short)(g2.y >> 16));
      a0 += n3 * bf2f((unsigned short)(g3.x & 0xffffu));
      a1 += n3 * bf2f((unsigned short)(g3.x >> 16));
      a2 += n3 * bf2f((unsigned short)(g3.y & 0xffffu));
      a3 += n3 * bf2f((unsigned short)(g3.y >> 16));
    }
    for (; e < end; ++e) {
      int2 p0 = pay[e];
      uint2 g0 = *(const uint2*)(Ag + (size_t)p0.x * DDIM + h * 4);
      float n0 = __int_as_float(p0.y);
      sn += n0;
      a0 += n0 * bf2f((unsigned short)(g0.x & 0xffffu));
      a1 += n0 * bf2f((unsigned short)(g0.x >> 16));
      a2 += n0 * bf2f((unsigned short)(g0.y & 0xffffu));
      a3 += n0 * bf2f((unsigned short)(g0.y >> 16));
    }

    uint2 av = *(const uint2*)(Ac + (size_t)r * DDIM + h * 4);
    uint2 qv = *(const uint2*)(Qc + (size_t)r * DDIM + h * 4);
    const float s1 = sn - 1.0f;
    float v0 = bf2f((unsigned short)(av.x & 0xffffu)) + s1 * bf2f((unsigned short)(qv.x & 0xffffu)) - b2v[0] + a0;
    float v1 = bf2f((unsigned short)(av.x >> 16))     + s1 * bf2f((unsigned short)(qv.x >> 16))     - b2v[1] + a1;
    float v2 = bf2f((unsigned short)(av.y & 0xffffu)) + s1 * bf2f((unsigned short)(qv.y & 0xffffu)) - b2v[2] + a2;
    float v3 = bf2f((unsigned short)(av.y >> 16))     + s1 * bf2f((unsigned short)(qv.y >> 16))     - b2v[3] + a3;

    v0 = v0 > 0.f ? v0 : 0.2f * v0;
    v1 = v1 > 0.f ? v1 : 0.2f * v1;
    v2 = v2 > 0.f ? v2 : 0.2f * v2;
    v3 = v3 > 0.f ? v3 : 0.2f * v3;
    float sq = v0 * v0 + v1 * v1 + v2 * v2 + v3 * v3;
#pragma unroll
    for (int off = 16; off; off >>= 1) sq += __shfl_xor(sq, off);
    float sc = 1.0f / fmaxf(sqrtf(sq), 1e-12f);
    f32x4 res;
    res.x = v0 * sc; res.y = v1 * sc; res.z = v2 * sc; res.w = v3 * sc;
    __builtin_nontemporal_store(res, (f32x4*)(out + (size_t)r * DDIM + h * 4));
  }
}

extern "C" void kernel_launch(void* const* d_in, const int* in_sizes, int n_in,
                              void* d_out, int out_size, void* d_ws, size_t ws_size,
                              hipStream_t stream) {
  const float* x_user  = (const float*)d_in[0];
  const float* x_item  = (const float*)d_in[1];
  const float* W1      = (const float*)d_in[2];
  const float* b1      = (const float*)d_in[3];
  const float* W2      = (const float*)d_in[4];
  const float* b2      = (const float*)d_in[5];
  const int*   src_ui  = (const int*)d_in[6];
  const int*   dst_ui  = (const int*)d_in[7];
  const float* norm_ui = (const float*)d_in[8];
  const int*   src_iu  = (const int*)d_in[9];
  const int*   dst_iu  = (const int*)d_in[10];
  const float* norm_iu = (const float*)d_in[11];

  const int NUr   = in_sizes[0] / DDIM;   // 100000
  const int NIr   = in_sizes[1] / DDIM;   // 50000
  const int nE_ui = in_sizes[6];          // 300000
  const int nE_iu = in_sizes[9];
  const int nTot  = NUr + NIr;
  const int nETot = nE_ui + nE_iu;

  float* out = (float*)d_out;             // rows: [h_user (NUr); h_item (NIr)]

  char* ws = (char*)d_ws;
  size_t off = 0;
  auto alloc = [&](size_t bytes) { char* p = ws + off; off += (bytes + 15) & ~(size_t)15; return p; };
  unsigned short* wb  = (unsigned short*)alloc(32768 * 2);
  unsigned short* Ac  = (unsigned short*)alloc((size_t)nTot * DDIM * 2);  // [Au; Ai]
  unsigned short* Qc  = (unsigned short*)alloc((size_t)nTot * DDIM * 2);  // [Qu; Qi]
  int*   deg          = (int*)alloc((size_t)nTot * 4);
  int*   exsc         = (int*)alloc((size_t)nTot * 4);
  int*   bsum         = (int*)alloc(256 * 4);
  int*   rowptr       = (int*)alloc(((size_t)nTot + 1) * 4);
  int*   rank         = (int*)alloc((size_t)nETot * 4);
  int2*  pay          = (int2*)alloc((size_t)nETot * 8);

  unsigned short* Au = Ac;
  unsigned short* Ai = Ac + (size_t)NUr * DDIM;
  unsigned short* Qu = Qc;
  unsigned short* Qi = Qc + (size_t)NUr * DDIM;

  (void)hipMemsetAsync(deg, 0, (size_t)nTot * 4, stream);

  const int gU = (NUr + 63) / 64;         // 1563
  const int gI = (NIr + 63) / 64;         // 782
  const int nTiles = gU + gI;             // 2345

  convW<<<128, 256, 0, stream>>>(W1, W2, wb);
  proj<<<1024, 256, 0, stream>>>(x_user, NUr, gU, x_item, NIr, nTiles,
                                 wb, b1, b2, Au, Qu, Ai, Qi);
  hist<<<4096, 256, 0, stream>>>(dst_ui, nE_ui, dst_iu, nE_iu, NUr, deg, rank);

  const int nb = (nTot + 1023) / 1024;    // 147
  scan1<<<nb, 1024, 0, stream>>>(deg, nTot, exsc, bsum);
  scan2<<<1, 256, 0, stream>>>(bsum, nb);
  scan3<<<(nTot + 256) / 256, 256, 0, stream>>>(exsc, bsum, nTot, nETot, rowptr);
  fillcsr<<<2048, 256, 0, stream>>>(src_ui, dst_ui, norm_ui, nE_ui,
                                    src_iu, dst_iu, norm_iu, nE_iu, NUr, rowptr, rank, pay);
  pullfin<<<18752, 256, 0, stream>>>(rowptr, pay, Ac, Au, Ai, Qc, b2, out, NUr, nTot);
}

// Round 14
// 146.490 us; speedup vs baseline: 1.1601x; 1.1601x over previous
//
#include <hip/hip_runtime.h>
#include <hip/hip_bf16.h>
#include <stdint.h>

typedef __attribute__((ext_vector_type(8))) short short8;
typedef __attribute__((ext_vector_type(4))) float f32x4;

#define DDIM 128

__device__ __forceinline__ unsigned short f2bf(float f) {
  union { float f; unsigned u; } v; v.f = f;
  unsigned u = v.u + 0x7FFFu + ((v.u >> 16) & 1u);  // RNE
  return (unsigned short)(u >> 16);
}
__device__ __forceinline__ float bf2f(unsigned short b) {
  union { unsigned u; float f; } v; v.u = ((unsigned)b) << 16;
  return v.f;
}
// packed f32 pair -> 2x bf16 in one u32 (v_cvt_pk_bf16_f32, RNE)
__device__ __forceinline__ unsigned pack2(float lo, float hi) {
  __hip_bfloat162 h2 = __float22bfloat162_rn(make_float2(lo, hi));
  unsigned u; __builtin_memcpy(&u, &h2, 4); return u;
}

// ---- weights fp32 -> bf16 staging: wb = [W1 rows; W2 rows] = [256][128]
__global__ void convW(const float* __restrict__ W1, const float* __restrict__ W2,
                      unsigned short* __restrict__ wb) {
  int i = blockIdx.x * blockDim.x + threadIdx.x;
  if (i < 16384)      wb[i] = f2bf(W1[i]);
  else if (i < 32768) wb[i] = f2bf(W2[i - 16384]);
}

// ---- proj v7: 8 waves/block, each wave owns 16 cols (both W1,W2).
//      wf = 32 VGPR, acc = 32 VGPR -> W stays register-resident, staged loads
//      keep concurrency. LDS xs staged + XOR swizzle; swapped-operand MFMA;
//      packed 8B stores.
__global__ __launch_bounds__(512) void proj(
    const float* __restrict__ xu, int NUr, int gU,
    const float* __restrict__ xi, int NIr, int nTiles,
    const unsigned short* __restrict__ wb,
    const float* __restrict__ b1, const float* __restrict__ b2,
    unsigned short* __restrict__ Au, unsigned short* __restrict__ Qu,
    unsigned short* __restrict__ Ai, unsigned short* __restrict__ Qi) {
  __shared__ unsigned short xs[64 * DDIM];   // 16 KB
  const int tid   = threadIdx.x;
  const int lane  = tid & 63;
  const int wv    = tid >> 6;                // 0..7
  const int col16 = lane & 15;
  const int kgrp  = lane >> 4;

  // W fragments once per block: wave wv covers cols [wv*16, wv*16+16) for m=0,1
  short8 wf[2][4];
#pragma unroll
  for (int m = 0; m < 2; ++m) {
    const int c = m * 128 + wv * 16 + col16;
#pragma unroll
    for (int ks = 0; ks < 4; ++ks)
      wf[m][ks] = *(const short8*)(wb + (size_t)c * DDIM + ks * 32 + kgrp * 8);
  }
  // bias for the 4 consecutive cols this thread owns
  float4 bc12;
  {
    const int cb = wv * 16 + kgrp * 4;
    float4 v1 = *(const float4*)(b1 + cb);
    float4 v2 = *(const float4*)(b2 + cb);
    bc12 = make_float4(v1.x + v2.x, v1.y + v2.y, v1.z + v2.z, v1.w + v2.w);
  }

  for (int t = blockIdx.x; t < nTiles; t += gridDim.x) {
    const bool isU = (t < gU);
    const float* __restrict__ x = isU ? xu : xi;
    const int nrows = isU ? NUr : NIr;
    const int tt    = isU ? t : (t - gU);
    unsigned short* __restrict__ Aout = isU ? Au : Ai;
    unsigned short* __restrict__ Qout = isU ? Qu : Qi;
    const int r0 = tt * 64;

    // ---- stage 64x128 f32 -> bf16 LDS, coalesced (512 thr x 4 float4)
#pragma unroll
    for (int i = 0; i < 4; ++i) {
      const int flat = i * 2048 + tid * 4;
      const int rr = flat >> 7, cc = flat & 127;
      float4 v;
      if (r0 + rr < nrows) v = *(const float4*)(x + (size_t)(r0 + rr) * DDIM + cc);
      else                 v = make_float4(0.f, 0.f, 0.f, 0.f);
      uint2 pk;
      pk.x = pack2(v.x, v.y);
      pk.y = pack2(v.z, v.w);
      const int byte = (rr * 256 + cc * 2) ^ ((rr & 7) << 4);
      *(uint2*)((char*)xs + byte) = pk;
    }
    __syncthreads();

    // ---- MFMA: acc[rt][m], wave's 16 cols x 64 rows
    f32x4 acc[4][2];
#pragma unroll
    for (int rt = 0; rt < 4; ++rt)
#pragma unroll
      for (int m = 0; m < 2; ++m)
        acc[rt][m] = (f32x4){0.f, 0.f, 0.f, 0.f};

#pragma unroll
    for (int ks = 0; ks < 4; ++ks) {
#pragma unroll
      for (int rt = 0; rt < 4; ++rt) {
        const int rr = rt * 16 + col16;
        const int byte = (rr * 256 + (ks * 64 + kgrp * 16)) ^ ((rr & 7) << 4);
        short8 a = *(const short8*)((char*)xs + byte);
#pragma unroll
        for (int m = 0; m < 2; ++m)
          acc[rt][m] = __builtin_amdgcn_mfma_f32_16x16x32_bf16(wf[m][ks], a, acc[rt][m], 0, 0, 0);
      }
    }

    // ---- epilogue: thread owns row r = r0+rt*16+col16, cols cb..cb+3
#pragma unroll
    for (int rt = 0; rt < 4; ++rt) {
      const int r = r0 + rt * 16 + col16;
      if (r < nrows) {
        const int cb = wv * 16 + kgrp * 4;
        const f32x4 y1 = acc[rt][0];
        const f32x4 y2 = acc[rt][1];
        uint2 ap, qp;
        ap.x = pack2(y1[0] + y2[0] + bc12.x, y1[1] + y2[1] + bc12.y);
        ap.y = pack2(y1[2] + y2[2] + bc12.z, y1[3] + y2[3] + bc12.w);
        qp.x = pack2(y2[0], y2[1]);
        qp.y = pack2(y2[2], y2[3]);
        *(uint2*)(Aout + (size_t)r * DDIM + cb) = ap;
        *(uint2*)(Qout + (size_t)r * DDIM + cb) = qp;
      }
    }
    __syncthreads();  // protect xs before next tile's stage
  }
}

// ---- hist: rank[i] = per-dst arrival index; ONE atomic per edge.
__global__ void hist(const int* __restrict__ dst_ui, int nE_ui,
                     const int* __restrict__ dst_iu, int nE_iu,
                     int NU, int* __restrict__ deg, int* __restrict__ rank) {
  int i = blockIdx.x * blockDim.x + threadIdx.x;
  const int stride = gridDim.x * blockDim.x;
  const int nTot = nE_ui + nE_iu;
  for (; i < nTot; i += stride) {
    const int d = (i < nE_ui) ? (NU + dst_ui[i]) : dst_iu[i - nE_ui];
    rank[i] = atomicAdd(&deg[d], 1);
  }
}

__global__ __launch_bounds__(1024) void scan1(const int* __restrict__ deg, int n,
                                              int* __restrict__ exsc, int* __restrict__ bsum) {
  __shared__ int wsum[16];
  const int tid = threadIdx.x;
  const int g = blockIdx.x * 1024 + tid;
  const int lane = tid & 63, wv = tid >> 6;
  int v = (g < n) ? deg[g] : 0;
  int x = v;
#pragma unroll
  for (int off = 1; off < 64; off <<= 1) {
    int y = __shfl_up(x, off);
    if (lane >= off) x += y;
  }
  if (lane == 63) wsum[wv] = x;
  __syncthreads();
  if (wv == 0 && lane < 16) {
    int s = wsum[lane];
#pragma unroll
    for (int off = 1; off < 16; off <<= 1) {
      int y = __shfl_up(s, off);
      if (lane >= off) s += y;
    }
    wsum[lane] = s;
  }
  __syncthreads();
  int woff = (wv == 0) ? 0 : wsum[wv - 1];
  int inc = x + woff;
  if (g < n) exsc[g] = inc - v;
  if (tid == 1023) bsum[blockIdx.x] = inc;
}

__global__ __launch_bounds__(256) void scan2(int* __restrict__ bsum, int nb) {
  __shared__ int tmp[256];
  const int tid = threadIdx.x;
  int v = (tid < nb) ? bsum[tid] : 0;
  int x = v;
  tmp[tid] = v;
  __syncthreads();
#pragma unroll
  for (int off = 1; off < 256; off <<= 1) {
    int y = (tid >= off) ? tmp[tid - off] : 0;
    __syncthreads();
    x += y;
    tmp[tid] = x;
    __syncthreads();
  }
  if (tid < nb) bsum[tid] = x - v;
}

__global__ void scan3(const int* __restrict__ exsc, const int* __restrict__ bsum,
                      int n, int nETot, int* __restrict__ rowptr) {
  int g = blockIdx.x * blockDim.x + threadIdx.x;
  if (g < n) rowptr[g] = exsc[g] + bsum[g >> 10];
  if (g == n) rowptr[n] = nETot;
}

// ---- fillcsr: ATOMIC-FREE — pos = rowptr[dst] + rank[i]
__global__ void fillcsr(const int* __restrict__ src_ui, const int* __restrict__ dst_ui,
                        const float* __restrict__ nrm_ui, int nE_ui,
                        const int* __restrict__ src_iu, const int* __restrict__ dst_iu,
                        const float* __restrict__ nrm_iu, int nE_iu,
                        int NU, const int* __restrict__ rowptr,
                        const int* __restrict__ rank, int2* __restrict__ pay) {
  int i = blockIdx.x * blockDim.x + threadIdx.x;
  int stride = gridDim.x * blockDim.x;
  int nTot = nE_ui + nE_iu;
  for (; i < nTot; i += stride) {
    int d, s; float nm;
    if (i < nE_ui) { d = NU + dst_ui[i]; s = src_ui[i]; nm = nrm_ui[i]; }
    else { int k = i - nE_ui; d = dst_iu[k]; s = src_iu[k]; nm = nrm_iu[k]; }
    const int pos = rowptr[d] + rank[i];
    int2 p; p.x = s; p.y = __float_as_int(nm);
    pay[pos] = p;
  }
}

// ---- pullfin v3: S computed inline from payload norms.
// h[r] = A_self[r] + (S-1)*Q[r] - b2 + sum_e norm_e * A_gather[src_e]; lrelu+L2norm.
__global__ __launch_bounds__(256) void pullfin(
    const int* __restrict__ rowptr, const int2* __restrict__ pay,
    const unsigned short* __restrict__ Ac,
    const unsigned short* __restrict__ Au, const unsigned short* __restrict__ Ai,
    const unsigned short* __restrict__ Qc,
    const float* __restrict__ b2,
    float* __restrict__ out, int NU, int ntot) {
  const int lane = threadIdx.x & 63;
  const int h    = lane & 31;
  const int half = lane >> 5;
  float b2v[4];
#pragma unroll
  for (int j = 0; j < 4; ++j) b2v[j] = b2[h * 4 + j];

  int r = (((blockIdx.x * blockDim.x + threadIdx.x) >> 6) << 1) + half;
  const int rstride = ((gridDim.x * blockDim.x) >> 6) << 1;
  for (; r < ntot; r += rstride) {
    const unsigned short* Ag = (r < NU) ? Ai : Au;
    const int beg = rowptr[r], end = rowptr[r + 1];
    float a0 = 0.f, a1 = 0.f, a2 = 0.f, a3 = 0.f, sn = 0.f;
    int e = beg;
    for (; e + 3 < end; e += 4) {
      int2 p0 = pay[e], p1 = pay[e + 1], p2 = pay[e + 2], p3 = pay[e + 3];
      uint2 g0 = *(const uint2*)(Ag + (size_t)p0.x * DDIM + h * 4);
      uint2 g1 = *(const uint2*)(Ag + (size_t)p1.x * DDIM + h * 4);
      uint2 g2 = *(const uint2*)(Ag + (size_t)p2.x * DDIM + h * 4);
      uint2 g3 = *(const uint2*)(Ag + (size_t)p3.x * DDIM + h * 4);
      float n0 = __int_as_float(p0.y), n1 = __int_as_float(p1.y);
      float n2 = __int_as_float(p2.y), n3 = __int_as_float(p3.y);
      sn += (n0 + n1) + (n2 + n3);
      a0 += n0 * bf2f((unsigned short)(g0.x & 0xffffu));
      a1 += n0 * bf2f((unsigned short)(g0.x >> 16));
      a2 += n0 * bf2f((unsigned short)(g0.y & 0xffffu));
      a3 += n0 * bf2f((unsigned short)(g0.y >> 16));
      a0 += n1 * bf2f((unsigned short)(g1.x & 0xffffu));
      a1 += n1 * bf2f((unsigned short)(g1.x >> 16));
      a2 += n1 * bf2f((unsigned short)(g1.y & 0xffffu));
      a3 += n1 * bf2f((unsigned short)(g1.y >> 16));
      a0 += n2 * bf2f((unsigned short)(g2.x & 0xffffu));
      a1 += n2 * bf2f((unsigned short)(g2.x >> 16));
      a2 += n2 * bf2f((unsigned short)(g2.y & 0xffffu));
      a3 += n2 * bf2f((unsigned short)(g2.y >> 16));
      a0 += n3 * bf2f((unsigned short)(g3.x & 0xffffu));
      a1 += n3 * bf2f((unsigned short)(g3.x >> 16));
      a2 += n3 * bf2f((unsigned short)(g3.y & 0xffffu));
      a3 += n3 * bf2f((unsigned short)(g3.y >> 16));
    }
    for (; e < end; ++e) {
      int2 p0 = pay[e];
      uint2 g0 = *(const uint2*)(Ag + (size_t)p0.x * DDIM + h * 4);
      float n0 = __int_as_float(p0.y);
      sn += n0;
      a0 += n0 * bf2f((unsigned short)(g0.x & 0xffffu));
      a1 += n0 * bf2f((unsigned short)(g0.x >> 16));
      a2 += n0 * bf2f((unsigned short)(g0.y & 0xffffu));
      a3 += n0 * bf2f((unsigned short)(g0.y >> 16));
    }

    uint2 av = *(const uint2*)(Ac + (size_t)r * DDIM + h * 4);
    uint2 qv = *(const uint2*)(Qc + (size_t)r * DDIM + h * 4);
    const float s1 = sn - 1.0f;
    float v0 = bf2f((unsigned short)(av.x & 0xffffu)) + s1 * bf2f((unsigned short)(qv.x & 0xffffu)) - b2v[0] + a0;
    float v1 = bf2f((unsigned short)(av.x >> 16))     + s1 * bf2f((unsigned short)(qv.x >> 16))     - b2v[1] + a1;
    float v2 = bf2f((unsigned short)(av.y & 0xffffu)) + s1 * bf2f((unsigned short)(qv.y & 0xffffu)) - b2v[2] + a2;
    float v3 = bf2f((unsigned short)(av.y >> 16))     + s1 * bf2f((unsigned short)(qv.y >> 16))     - b2v[3] + a3;

    v0 = v0 > 0.f ? v0 : 0.2f * v0;
    v1 = v1 > 0.f ? v1 : 0.2f * v1;
    v2 = v2 > 0.f ? v2 : 0.2f * v2;
    v3 = v3 > 0.f ? v3 : 0.2f * v3;
    float sq = v0 * v0 + v1 * v1 + v2 * v2 + v3 * v3;
#pragma unroll
    for (int off = 16; off; off >>= 1) sq += __shfl_xor(sq, off);
    float sc = 1.0f / fmaxf(sqrtf(sq), 1e-12f);
    f32x4 res;
    res.x = v0 * sc; res.y = v1 * sc; res.z = v2 * sc; res.w = v3 * sc;
    __builtin_nontemporal_store(res, (f32x4*)(out + (size_t)r * DDIM + h * 4));
  }
}

extern "C" void kernel_launch(void* const* d_in, const int* in_sizes, int n_in,
                              void* d_out, int out_size, void* d_ws, size_t ws_size,
                              hipStream_t stream) {
  const float* x_user  = (const float*)d_in[0];
  const float* x_item  = (const float*)d_in[1];
  const float* W1      = (const float*)d_in[2];
  const float* b1      = (const float*)d_in[3];
  const float* W2      = (const float*)d_in[4];
  const float* b2      = (const float*)d_in[5];
  const int*   src_ui  = (const int*)d_in[6];
  const int*   dst_ui  = (const int*)d_in[7];
  const float* norm_ui = (const float*)d_in[8];
  const int*   src_iu  = (const int*)d_in[9];
  const int*   dst_iu  = (const int*)d_in[10];
  const float* norm_iu = (const float*)d_in[11];

  const int NUr   = in_sizes[0] / DDIM;   // 100000
  const int NIr   = in_sizes[1] / DDIM;   // 50000
  const int nE_ui = in_sizes[6];          // 300000
  const int nE_iu = in_sizes[9];
  const int nTot  = NUr + NIr;
  const int nETot = nE_ui + nE_iu;

  float* out = (float*)d_out;             // rows: [h_user (NUr); h_item (NIr)]

  char* ws = (char*)d_ws;
  size_t off = 0;
  auto alloc = [&](size_t bytes) { char* p = ws + off; off += (bytes + 15) & ~(size_t)15; return p; };
  unsigned short* wb  = (unsigned short*)alloc(32768 * 2);
  unsigned short* Ac  = (unsigned short*)alloc((size_t)nTot * DDIM * 2);  // [Au; Ai]
  unsigned short* Qc  = (unsigned short*)alloc((size_t)nTot * DDIM * 2);  // [Qu; Qi]
  int*   deg          = (int*)alloc((size_t)nTot * 4);
  int*   exsc         = (int*)alloc((size_t)nTot * 4);
  int*   bsum         = (int*)alloc(256 * 4);
  int*   rowptr       = (int*)alloc(((size_t)nTot + 1) * 4);
  int*   rank         = (int*)alloc((size_t)nETot * 4);
  int2*  pay          = (int2*)alloc((size_t)nETot * 8);

  unsigned short* Au = Ac;
  unsigned short* Ai = Ac + (size_t)NUr * DDIM;
  unsigned short* Qu = Qc;
  unsigned short* Qi = Qc + (size_t)NUr * DDIM;

  (void)hipMemsetAsync(deg, 0, (size_t)nTot * 4, stream);

  const int gU = (NUr + 63) / 64;         // 1563
  const int gI = (NIr + 63) / 64;         // 782
  const int nTiles = gU + gI;             // 2345

  convW<<<128, 256, 0, stream>>>(W1, W2, wb);
  proj<<<512, 512, 0, stream>>>(x_user, NUr, gU, x_item, NIr, nTiles,
                                wb, b1, b2, Au, Qu, Ai, Qi);
  hist<<<4096, 256, 0, stream>>>(dst_ui, nE_ui, dst_iu, nE_iu, NUr, deg, rank);

  const int nb = (nTot + 1023) / 1024;    // 147
  scan1<<<nb, 1024, 0, stream>>>(deg, nTot, exsc, bsum);
  scan2<<<1, 256, 0, stream>>>(bsum, nb);
  scan3<<<(nTot + 256) / 256, 256, 0, stream>>>(exsc, bsum, nTot, nETot, rowptr);
  fillcsr<<<2048, 256, 0, stream>>>(src_ui, dst_ui, norm_ui, nE_ui,
                                    src_iu, dst_iu, norm_iu, nE_iu, NUr, rowptr, rank, pay);
  pullfin<<<18752, 256, 0, stream>>>(rowptr, pay, Ac, Au, Ai, Qc, b2, out, NUr, nTot);
}

// Round 15
// 135.691 us; speedup vs baseline: 1.2524x; 1.0796x over previous
//
#include <hip/hip_runtime.h>
#include <hip/hip_bf16.h>
#include <stdint.h>

typedef __attribute__((ext_vector_type(8))) short short8;
typedef __attribute__((ext_vector_type(4))) float f32x4;

#define DDIM 128

__device__ __forceinline__ unsigned short f2bf(float f) {
  union { float f; unsigned u; } v; v.f = f;
  unsigned u = v.u + 0x7FFFu + ((v.u >> 16) & 1u);  // RNE
  return (unsigned short)(u >> 16);
}
__device__ __forceinline__ float bf2f(unsigned short b) {
  union { unsigned u; float f; } v; v.u = ((unsigned)b) << 16;
  return v.f;
}
// packed f32 pair -> 2x bf16 in one u32 (v_cvt_pk_bf16_f32, RNE)
__device__ __forceinline__ unsigned pack2(float lo, float hi) {
  __hip_bfloat162 h2 = __float22bfloat162_rn(make_float2(lo, hi));
  unsigned u; __builtin_memcpy(&u, &h2, 4); return u;
}
__device__ __forceinline__ void acc8(float* a, float n, uint4 g) {
  a[0] += n * bf2f((unsigned short)(g.x & 0xffffu));
  a[1] += n * bf2f((unsigned short)(g.x >> 16));
  a[2] += n * bf2f((unsigned short)(g.y & 0xffffu));
  a[3] += n * bf2f((unsigned short)(g.y >> 16));
  a[4] += n * bf2f((unsigned short)(g.z & 0xffffu));
  a[5] += n * bf2f((unsigned short)(g.z >> 16));
  a[6] += n * bf2f((unsigned short)(g.w & 0xffffu));
  a[7] += n * bf2f((unsigned short)(g.w >> 16));
}

// ---- weights fp32 -> bf16 staging: wb = [W1 rows; W2 rows] = [256][128]
__global__ void convW(const float* __restrict__ W1, const float* __restrict__ W2,
                      unsigned short* __restrict__ wb) {
  int i = blockIdx.x * blockDim.x + threadIdx.x;
  if (i < 16384)      wb[i] = f2bf(W1[i]);
  else if (i < 32768) wb[i] = f2bf(W2[i - 16384]);
}

// ---- proj v8: v7 (8 waves, 16 cols/wave, register-resident W) + hist tail.
//      After the tile loop each block grid-strides an edge chunk doing the
//      rank/deg atomic — hist hides under proj's tail instead of serializing.
__global__ __launch_bounds__(512) void proj(
    const float* __restrict__ xu, int NUr, int gU,
    const float* __restrict__ xi, int NIr, int nTiles,
    const unsigned short* __restrict__ wb,
    const float* __restrict__ b1, const float* __restrict__ b2,
    unsigned short* __restrict__ Au, unsigned short* __restrict__ Qu,
    unsigned short* __restrict__ Ai, unsigned short* __restrict__ Qi,
    const int* __restrict__ dst_ui, int nE_ui,
    const int* __restrict__ dst_iu, int nE_iu,
    int* __restrict__ deg, int* __restrict__ rank) {
  __shared__ unsigned short xs[64 * DDIM];   // 16 KB
  const int tid   = threadIdx.x;
  const int lane  = tid & 63;
  const int wv    = tid >> 6;                // 0..7
  const int col16 = lane & 15;
  const int kgrp  = lane >> 4;

  short8 wf[2][4];
#pragma unroll
  for (int m = 0; m < 2; ++m) {
    const int c = m * 128 + wv * 16 + col16;
#pragma unroll
    for (int ks = 0; ks < 4; ++ks)
      wf[m][ks] = *(const short8*)(wb + (size_t)c * DDIM + ks * 32 + kgrp * 8);
  }
  float4 bc12;
  {
    const int cb = wv * 16 + kgrp * 4;
    float4 v1 = *(const float4*)(b1 + cb);
    float4 v2 = *(const float4*)(b2 + cb);
    bc12 = make_float4(v1.x + v2.x, v1.y + v2.y, v1.z + v2.z, v1.w + v2.w);
  }

  for (int t = blockIdx.x; t < nTiles; t += gridDim.x) {
    const bool isU = (t < gU);
    const float* __restrict__ x = isU ? xu : xi;
    const int nrows = isU ? NUr : NIr;
    const int tt    = isU ? t : (t - gU);
    unsigned short* __restrict__ Aout = isU ? Au : Ai;
    unsigned short* __restrict__ Qout = isU ? Qu : Qi;
    const int r0 = tt * 64;

#pragma unroll
    for (int i = 0; i < 4; ++i) {
      const int flat = i * 2048 + tid * 4;
      const int rr = flat >> 7, cc = flat & 127;
      float4 v;
      if (r0 + rr < nrows) v = *(const float4*)(x + (size_t)(r0 + rr) * DDIM + cc);
      else                 v = make_float4(0.f, 0.f, 0.f, 0.f);
      uint2 pk;
      pk.x = pack2(v.x, v.y);
      pk.y = pack2(v.z, v.w);
      const int byte = (rr * 256 + cc * 2) ^ ((rr & 7) << 4);
      *(uint2*)((char*)xs + byte) = pk;
    }
    __syncthreads();

    f32x4 acc[4][2];
#pragma unroll
    for (int rt = 0; rt < 4; ++rt)
#pragma unroll
      for (int m = 0; m < 2; ++m)
        acc[rt][m] = (f32x4){0.f, 0.f, 0.f, 0.f};

#pragma unroll
    for (int ks = 0; ks < 4; ++ks) {
#pragma unroll
      for (int rt = 0; rt < 4; ++rt) {
        const int rr = rt * 16 + col16;
        const int byte = (rr * 256 + (ks * 64 + kgrp * 16)) ^ ((rr & 7) << 4);
        short8 a = *(const short8*)((char*)xs + byte);
#pragma unroll
        for (int m = 0; m < 2; ++m)
          acc[rt][m] = __builtin_amdgcn_mfma_f32_16x16x32_bf16(wf[m][ks], a, acc[rt][m], 0, 0, 0);
      }
    }

#pragma unroll
    for (int rt = 0; rt < 4; ++rt) {
      const int r = r0 + rt * 16 + col16;
      if (r < nrows) {
        const int cb = wv * 16 + kgrp * 4;
        const f32x4 y1 = acc[rt][0];
        const f32x4 y2 = acc[rt][1];
        uint2 ap, qp;
        ap.x = pack2(y1[0] + y2[0] + bc12.x, y1[1] + y2[1] + bc12.y);
        ap.y = pack2(y1[2] + y2[2] + bc12.z, y1[3] + y2[3] + bc12.w);
        qp.x = pack2(y2[0], y2[1]);
        qp.y = pack2(y2[2], y2[3]);
        *(uint2*)(Aout + (size_t)r * DDIM + cb) = ap;
        *(uint2*)(Qout + (size_t)r * DDIM + cb) = qp;
      }
    }
    __syncthreads();  // protect xs before next tile's stage
  }

  // ---- hist tail: rank[i] = per-dst arrival index; ONE atomic per edge.
  const int nETot = nE_ui + nE_iu;
  const int gsz = gridDim.x * 512;
  for (int i = blockIdx.x * 512 + tid; i < nETot; i += gsz) {
    const int d = (i < nE_ui) ? (NUr + dst_ui[i]) : dst_iu[i - nE_ui];
    rank[i] = atomicAdd(&deg[d], 1);
  }
}

__global__ __launch_bounds__(1024) void scan1(const int* __restrict__ deg, int n,
                                              int* __restrict__ exsc, int* __restrict__ bsum) {
  __shared__ int wsum[16];
  const int tid = threadIdx.x;
  const int g = blockIdx.x * 1024 + tid;
  const int lane = tid & 63, wv = tid >> 6;
  int v = (g < n) ? deg[g] : 0;
  int x = v;
#pragma unroll
  for (int off = 1; off < 64; off <<= 1) {
    int y = __shfl_up(x, off);
    if (lane >= off) x += y;
  }
  if (lane == 63) wsum[wv] = x;
  __syncthreads();
  if (wv == 0 && lane < 16) {
    int s = wsum[lane];
#pragma unroll
    for (int off = 1; off < 16; off <<= 1) {
      int y = __shfl_up(s, off);
      if (lane >= off) s += y;
    }
    wsum[lane] = s;
  }
  __syncthreads();
  int woff = (wv == 0) ? 0 : wsum[wv - 1];
  int inc = x + woff;
  if (g < n) exsc[g] = inc - v;
  if (tid == 1023) bsum[blockIdx.x] = inc;
}

__global__ __launch_bounds__(256) void scan2(int* __restrict__ bsum, int nb) {
  __shared__ int tmp[256];
  const int tid = threadIdx.x;
  int v = (tid < nb) ? bsum[tid] : 0;
  int x = v;
  tmp[tid] = v;
  __syncthreads();
#pragma unroll
  for (int off = 1; off < 256; off <<= 1) {
    int y = (tid >= off) ? tmp[tid - off] : 0;
    __syncthreads();
    x += y;
    tmp[tid] = x;
    __syncthreads();
  }
  if (tid < nb) bsum[tid] = x - v;
}

__global__ void scan3(const int* __restrict__ exsc, const int* __restrict__ bsum,
                      int n, int nETot, int* __restrict__ rowptr) {
  int g = blockIdx.x * blockDim.x + threadIdx.x;
  if (g < n) rowptr[g] = exsc[g] + bsum[g >> 10];
  if (g == n) rowptr[n] = nETot;
}

// ---- fillcsr: ATOMIC-FREE — pos = rowptr[dst] + rank[i]
__global__ void fillcsr(const int* __restrict__ src_ui, const int* __restrict__ dst_ui,
                        const float* __restrict__ nrm_ui, int nE_ui,
                        const int* __restrict__ src_iu, const int* __restrict__ dst_iu,
                        const float* __restrict__ nrm_iu, int nE_iu,
                        int NU, const int* __restrict__ rowptr,
                        const int* __restrict__ rank, int2* __restrict__ pay) {
  int i = blockIdx.x * blockDim.x + threadIdx.x;
  int stride = gridDim.x * blockDim.x;
  int nTot = nE_ui + nE_iu;
  for (; i < nTot; i += stride) {
    int d, s; float nm;
    if (i < nE_ui) { d = NU + dst_ui[i]; s = src_ui[i]; nm = nrm_ui[i]; }
    else { int k = i - nE_ui; d = dst_iu[k]; s = src_iu[k]; nm = nrm_iu[k]; }
    const int pos = rowptr[d] + rank[i];
    int2 p; p.x = s; p.y = __float_as_int(nm);
    pay[pos] = p;
  }
}

// ---- pullfin v4: quarter-wave rows (16 lanes/row, 4 rows/wave), uint4
//      gathers (16B/lane), 4-deep unroll -> up to 16 outstanding gathers/wave.
// h[r] = A_self[r] + (S-1)*Q[r] - b2 + sum_e norm_e * A_gather[src_e]; lrelu+L2norm.
__global__ __launch_bounds__(256) void pullfin(
    const int* __restrict__ rowptr, const int2* __restrict__ pay,
    const unsigned short* __restrict__ Ac,
    const unsigned short* __restrict__ Au, const unsigned short* __restrict__ Ai,
    const unsigned short* __restrict__ Qc,
    const float* __restrict__ b2,
    float* __restrict__ out, int NU, int ntot) {
  const int lane = threadIdx.x & 63;
  const int h    = lane & 15;          // lane within quarter-wave
  const int q    = lane >> 4;          // quarter 0..3
  float b2v[8];
  {
    float4 lo = *(const float4*)(b2 + h * 8);
    float4 hi = *(const float4*)(b2 + h * 8 + 4);
    b2v[0] = lo.x; b2v[1] = lo.y; b2v[2] = lo.z; b2v[3] = lo.w;
    b2v[4] = hi.x; b2v[5] = hi.y; b2v[6] = hi.z; b2v[7] = hi.w;
  }

  int r = (((blockIdx.x * blockDim.x + threadIdx.x) >> 6) << 2) + q;
  const int rstride = ((gridDim.x * blockDim.x) >> 6) << 2;
  for (; r < ntot; r += rstride) {
    const unsigned short* Ag = (r < NU) ? Ai : Au;
    const int beg = rowptr[r], end = rowptr[r + 1];
    float a[8] = {0.f, 0.f, 0.f, 0.f, 0.f, 0.f, 0.f, 0.f};
    float sn = 0.f;
    int e = beg;
    for (; e + 3 < end; e += 4) {
      int2 p0 = pay[e], p1 = pay[e + 1], p2 = pay[e + 2], p3 = pay[e + 3];
      uint4 g0 = *(const uint4*)(Ag + (size_t)p0.x * DDIM + h * 8);
      uint4 g1 = *(const uint4*)(Ag + (size_t)p1.x * DDIM + h * 8);
      uint4 g2 = *(const uint4*)(Ag + (size_t)p2.x * DDIM + h * 8);
      uint4 g3 = *(const uint4*)(Ag + (size_t)p3.x * DDIM + h * 8);
      float n0 = __int_as_float(p0.y), n1 = __int_as_float(p1.y);
      float n2 = __int_as_float(p2.y), n3 = __int_as_float(p3.y);
      sn += (n0 + n1) + (n2 + n3);
      acc8(a, n0, g0);
      acc8(a, n1, g1);
      acc8(a, n2, g2);
      acc8(a, n3, g3);
    }
    for (; e < end; ++e) {
      int2 p0 = pay[e];
      uint4 g0 = *(const uint4*)(Ag + (size_t)p0.x * DDIM + h * 8);
      float n0 = __int_as_float(p0.y);
      sn += n0;
      acc8(a, n0, g0);
    }

    uint4 av = *(const uint4*)(Ac + (size_t)r * DDIM + h * 8);
    uint4 qv = *(const uint4*)(Qc + (size_t)r * DDIM + h * 8);
    const float s1 = sn - 1.0f;
    float v[8];
    v[0] = bf2f((unsigned short)(av.x & 0xffffu)) + s1 * bf2f((unsigned short)(qv.x & 0xffffu)) - b2v[0] + a[0];
    v[1] = bf2f((unsigned short)(av.x >> 16))     + s1 * bf2f((unsigned short)(qv.x >> 16))     - b2v[1] + a[1];
    v[2] = bf2f((unsigned short)(av.y & 0xffffu)) + s1 * bf2f((unsigned short)(qv.y & 0xffffu)) - b2v[2] + a[2];
    v[3] = bf2f((unsigned short)(av.y >> 16))     + s1 * bf2f((unsigned short)(qv.y >> 16))     - b2v[3] + a[3];
    v[4] = bf2f((unsigned short)(av.z & 0xffffu)) + s1 * bf2f((unsigned short)(qv.z & 0xffffu)) - b2v[4] + a[4];
    v[5] = bf2f((unsigned short)(av.z >> 16))     + s1 * bf2f((unsigned short)(qv.z >> 16))     - b2v[5] + a[5];
    v[6] = bf2f((unsigned short)(av.w & 0xffffu)) + s1 * bf2f((unsigned short)(qv.w & 0xffffu)) - b2v[6] + a[6];
    v[7] = bf2f((unsigned short)(av.w >> 16))     + s1 * bf2f((unsigned short)(qv.w >> 16))     - b2v[7] + a[7];

    float sq = 0.f;
#pragma unroll
    for (int j = 0; j < 8; ++j) {
      v[j] = v[j] > 0.f ? v[j] : 0.2f * v[j];
      sq += v[j] * v[j];
    }
#pragma unroll
    for (int off = 8; off; off >>= 1) sq += __shfl_xor(sq, off);  // within 16-lane quarter
    float sc = 1.0f / fmaxf(sqrtf(sq), 1e-12f);
    f32x4 lo, hi;
    lo.x = v[0] * sc; lo.y = v[1] * sc; lo.z = v[2] * sc; lo.w = v[3] * sc;
    hi.x = v[4] * sc; hi.y = v[5] * sc; hi.z = v[6] * sc; hi.w = v[7] * sc;
    float* o = out + (size_t)r * DDIM + h * 8;
    __builtin_nontemporal_store(lo, (f32x4*)o);
    __builtin_nontemporal_store(hi, (f32x4*)(o + 4));
  }
}

extern "C" void kernel_launch(void* const* d_in, const int* in_sizes, int n_in,
                              void* d_out, int out_size, void* d_ws, size_t ws_size,
                              hipStream_t stream) {
  const float* x_user  = (const float*)d_in[0];
  const float* x_item  = (const float*)d_in[1];
  const float* W1      = (const float*)d_in[2];
  const float* b1      = (const float*)d_in[3];
  const float* W2      = (const float*)d_in[4];
  const float* b2      = (const float*)d_in[5];
  const int*   src_ui  = (const int*)d_in[6];
  const int*   dst_ui  = (const int*)d_in[7];
  const float* norm_ui = (const float*)d_in[8];
  const int*   src_iu  = (const int*)d_in[9];
  const int*   dst_iu  = (const int*)d_in[10];
  const float* norm_iu = (const float*)d_in[11];

  const int NUr   = in_sizes[0] / DDIM;   // 100000
  const int NIr   = in_sizes[1] / DDIM;   // 50000
  const int nE_ui = in_sizes[6];          // 300000
  const int nE_iu = in_sizes[9];
  const int nTot  = NUr + NIr;
  const int nETot = nE_ui + nE_iu;

  float* out = (float*)d_out;             // rows: [h_user (NUr); h_item (NIr)]

  char* ws = (char*)d_ws;
  size_t off = 0;
  auto alloc = [&](size_t bytes) { char* p = ws + off; off += (bytes + 15) & ~(size_t)15; return p; };
  unsigned short* wb  = (unsigned short*)alloc(32768 * 2);
  unsigned short* Ac  = (unsigned short*)alloc((size_t)nTot * DDIM * 2);  // [Au; Ai]
  unsigned short* Qc  = (unsigned short*)alloc((size_t)nTot * DDIM * 2);  // [Qu; Qi]
  int*   deg          = (int*)alloc((size_t)nTot * 4);
  int*   exsc         = (int*)alloc((size_t)nTot * 4);
  int*   bsum         = (int*)alloc(256 * 4);
  int*   rowptr       = (int*)alloc(((size_t)nTot + 1) * 4);
  int*   rank         = (int*)alloc((size_t)nETot * 4);
  int2*  pay          = (int2*)alloc((size_t)nETot * 8);

  unsigned short* Au = Ac;
  unsigned short* Ai = Ac + (size_t)NUr * DDIM;
  unsigned short* Qu = Qc;
  unsigned short* Qi = Qc + (size_t)NUr * DDIM;

  (void)hipMemsetAsync(deg, 0, (size_t)nTot * 4, stream);

  const int gU = (NUr + 63) / 64;         // 1563
  const int gI = (NIr + 63) / 64;         // 782
  const int nTiles = gU + gI;             // 2345

  convW<<<128, 256, 0, stream>>>(W1, W2, wb);
  proj<<<512, 512, 0, stream>>>(x_user, NUr, gU, x_item, NIr, nTiles,
                                wb, b1, b2, Au, Qu, Ai, Qi,
                                dst_ui, nE_ui, dst_iu, nE_iu, deg, rank);

  const int nb = (nTot + 1023) / 1024;    // 147
  scan1<<<nb, 1024, 0, stream>>>(deg, nTot, exsc, bsum);
  scan2<<<1, 256, 0, stream>>>(bsum, nb);
  scan3<<<(nTot + 256) / 256, 256, 0, stream>>>(exsc, bsum, nTot, nETot, rowptr);
  fillcsr<<<2048, 256, 0, stream>>>(src_ui, dst_ui, norm_ui, nE_ui,
                                    src_iu, dst_iu, norm_iu, nE_iu, NUr, rowptr, rank, pay);
  pullfin<<<9376, 256, 0, stream>>>(rowptr, pay, Ac, Au, Ai, Qc, b2, out, NUr, nTot);
}

// Round 16
// 128.467 us; speedup vs baseline: 1.3228x; 1.0562x over previous
//
#include <hip/hip_runtime.h>
#include <hip/hip_bf16.h>
#include <stdint.h>

typedef __attribute__((ext_vector_type(8))) short short8;
typedef __attribute__((ext_vector_type(4))) float f32x4;

#define DDIM 128

__device__ __forceinline__ unsigned short f2bf(float f) {
  union { float f; unsigned u; } v; v.f = f;
  unsigned u = v.u + 0x7FFFu + ((v.u >> 16) & 1u);  // RNE
  return (unsigned short)(u >> 16);
}
__device__ __forceinline__ float bf2f(unsigned short b) {
  union { unsigned u; float f; } v; v.u = ((unsigned)b) << 16;
  return v.f;
}
// packed f32 pair -> 2x bf16 in one u32 (v_cvt_pk_bf16_f32, RNE)
__device__ __forceinline__ unsigned pack2(float lo, float hi) {
  __hip_bfloat162 h2 = __float22bfloat162_rn(make_float2(lo, hi));
  unsigned u; __builtin_memcpy(&u, &h2, 4); return u;
}
__device__ __forceinline__ void acc8(float* a, float n, uint4 g) {
  a[0] += n * bf2f((unsigned short)(g.x & 0xffffu));
  a[1] += n * bf2f((unsigned short)(g.x >> 16));
  a[2] += n * bf2f((unsigned short)(g.y & 0xffffu));
  a[3] += n * bf2f((unsigned short)(g.y >> 16));
  a[4] += n * bf2f((unsigned short)(g.z & 0xffffu));
  a[5] += n * bf2f((unsigned short)(g.z >> 16));
  a[6] += n * bf2f((unsigned short)(g.w & 0xffffu));
  a[7] += n * bf2f((unsigned short)(g.w >> 16));
}

// ---- weights fp32 -> bf16 staging: wb = [W1 rows; W2 rows] = [256][128]
__global__ void convW(const float* __restrict__ W1, const float* __restrict__ W2,
                      unsigned short* __restrict__ wb) {
  int i = blockIdx.x * blockDim.x + threadIdx.x;
  if (i < 16384)      wb[i] = f2bf(W1[i]);
  else if (i < 32768) wb[i] = f2bf(W2[i - 16384]);
}

// ---- proj v9: v8 + SOFTWARE-PIPELINED hist. Per tile iteration each thread
//      issues one edge atomic right after the stage barrier and stores the
//      returned rank only after the MFMA block — atomic RT hides under MFMA.
__global__ __launch_bounds__(512) void proj(
    const float* __restrict__ xu, int NUr, int gU,
    const float* __restrict__ xi, int NIr, int nTiles,
    const unsigned short* __restrict__ wb,
    const float* __restrict__ b1, const float* __restrict__ b2,
    unsigned short* __restrict__ Au, unsigned short* __restrict__ Qu,
    unsigned short* __restrict__ Ai, unsigned short* __restrict__ Qi,
    const int* __restrict__ dst_ui, int nE_ui,
    const int* __restrict__ dst_iu, int nE_iu,
    int* __restrict__ deg, int* __restrict__ rank) {
  __shared__ unsigned short xs[64 * DDIM];   // 16 KB
  const int tid   = threadIdx.x;
  const int lane  = tid & 63;
  const int wv    = tid >> 6;                // 0..7
  const int col16 = lane & 15;
  const int kgrp  = lane >> 4;

  short8 wf[2][4];
#pragma unroll
  for (int m = 0; m < 2; ++m) {
    const int c = m * 128 + wv * 16 + col16;
#pragma unroll
    for (int ks = 0; ks < 4; ++ks)
      wf[m][ks] = *(const short8*)(wb + (size_t)c * DDIM + ks * 32 + kgrp * 8);
  }
  float4 bc12;
  {
    const int cb = wv * 16 + kgrp * 4;
    float4 v1 = *(const float4*)(b1 + cb);
    float4 v2 = *(const float4*)(b2 + cb);
    bc12 = make_float4(v1.x + v2.x, v1.y + v2.y, v1.z + v2.z, v1.w + v2.w);
  }

  // this block's edge share (processed pipelined inside the tile loop)
  const int nETot    = nE_ui + nE_iu;
  const int perBlock = (nETot + gridDim.x - 1) / gridDim.x;
  const int ebeg     = blockIdx.x * perBlock;
  const int eend     = (ebeg + perBlock < nETot) ? (ebeg + perBlock) : nETot;
  int ecur = ebeg + tid;

  for (int t = blockIdx.x; t < nTiles; t += gridDim.x) {
    const bool isU = (t < gU);
    const float* __restrict__ x = isU ? xu : xi;
    const int nrows = isU ? NUr : NIr;
    const int tt    = isU ? t : (t - gU);
    unsigned short* __restrict__ Aout = isU ? Au : Ai;
    unsigned short* __restrict__ Qout = isU ? Qu : Qi;
    const int r0 = tt * 64;

#pragma unroll
    for (int i = 0; i < 4; ++i) {
      const int flat = i * 2048 + tid * 4;
      const int rr = flat >> 7, cc = flat & 127;
      float4 v;
      if (r0 + rr < nrows) v = *(const float4*)(x + (size_t)(r0 + rr) * DDIM + cc);
      else                 v = make_float4(0.f, 0.f, 0.f, 0.f);
      uint2 pk;
      pk.x = pack2(v.x, v.y);
      pk.y = pack2(v.z, v.w);
      const int byte = (rr * 256 + cc * 2) ^ ((rr & 7) << 4);
      *(uint2*)((char*)xs + byte) = pk;
    }
    __syncthreads();

    // issue one edge atomic per thread; consume after MFMA (latency hidden)
    int pi = -1, pr = 0;
    if (ecur < eend) {
      const int d = (ecur < nE_ui) ? (NUr + dst_ui[ecur]) : dst_iu[ecur - nE_ui];
      pr = atomicAdd(&deg[d], 1);
      pi = ecur;
      ecur += 512;
    }

    f32x4 acc[4][2];
#pragma unroll
    for (int rt = 0; rt < 4; ++rt)
#pragma unroll
      for (int m = 0; m < 2; ++m)
        acc[rt][m] = (f32x4){0.f, 0.f, 0.f, 0.f};

#pragma unroll
    for (int ks = 0; ks < 4; ++ks) {
#pragma unroll
      for (int rt = 0; rt < 4; ++rt) {
        const int rr = rt * 16 + col16;
        const int byte = (rr * 256 + (ks * 64 + kgrp * 16)) ^ ((rr & 7) << 4);
        short8 a = *(const short8*)((char*)xs + byte);
#pragma unroll
        for (int m = 0; m < 2; ++m)
          acc[rt][m] = __builtin_amdgcn_mfma_f32_16x16x32_bf16(wf[m][ks], a, acc[rt][m], 0, 0, 0);
      }
    }

    if (pi >= 0) rank[pi] = pr;   // consume atomic return after MFMA

#pragma unroll
    for (int rt = 0; rt < 4; ++rt) {
      const int r = r0 + rt * 16 + col16;
      if (r < nrows) {
        const int cb = wv * 16 + kgrp * 4;
        const f32x4 y1 = acc[rt][0];
        const f32x4 y2 = acc[rt][1];
        uint2 ap, qp;
        ap.x = pack2(y1[0] + y2[0] + bc12.x, y1[1] + y2[1] + bc12.y);
        ap.y = pack2(y1[2] + y2[2] + bc12.z, y1[3] + y2[3] + bc12.w);
        qp.x = pack2(y2[0], y2[1]);
        qp.y = pack2(y2[2], y2[3]);
        *(uint2*)(Aout + (size_t)r * DDIM + cb) = ap;
        *(uint2*)(Qout + (size_t)r * DDIM + cb) = qp;
      }
    }
    __syncthreads();  // protect xs before next tile's stage
  }

  // tail: leftover edges for blocks with fewer tile iterations
  for (; ecur < eend; ecur += 512) {
    const int d = (ecur < nE_ui) ? (NUr + dst_ui[ecur]) : dst_iu[ecur - nE_ui];
    rank[ecur] = atomicAdd(&deg[d], 1);
  }
}

__global__ __launch_bounds__(1024) void scan1(const int* __restrict__ deg, int n,
                                              int* __restrict__ exsc, int* __restrict__ bsum) {
  __shared__ int wsum[16];
  const int tid = threadIdx.x;
  const int g = blockIdx.x * 1024 + tid;
  const int lane = tid & 63, wv = tid >> 6;
  int v = (g < n) ? deg[g] : 0;
  int x = v;
#pragma unroll
  for (int off = 1; off < 64; off <<= 1) {
    int y = __shfl_up(x, off);
    if (lane >= off) x += y;
  }
  if (lane == 63) wsum[wv] = x;
  __syncthreads();
  if (wv == 0 && lane < 16) {
    int s = wsum[lane];
#pragma unroll
    for (int off = 1; off < 16; off <<= 1) {
      int y = __shfl_up(s, off);
      if (lane >= off) s += y;
    }
    wsum[lane] = s;
  }
  __syncthreads();
  int woff = (wv == 0) ? 0 : wsum[wv - 1];
  int inc = x + woff;
  if (g < n) exsc[g] = inc - v;
  if (tid == 1023) bsum[blockIdx.x] = inc;
}

__global__ __launch_bounds__(256) void scan2(int* __restrict__ bsum, int nb) {
  __shared__ int tmp[256];
  const int tid = threadIdx.x;
  int v = (tid < nb) ? bsum[tid] : 0;
  int x = v;
  tmp[tid] = v;
  __syncthreads();
#pragma unroll
  for (int off = 1; off < 256; off <<= 1) {
    int y = (tid >= off) ? tmp[tid - off] : 0;
    __syncthreads();
    x += y;
    tmp[tid] = x;
    __syncthreads();
  }
  if (tid < nb) bsum[tid] = x - v;
}

__global__ void scan3(const int* __restrict__ exsc, const int* __restrict__ bsum,
                      int n, int nETot, int* __restrict__ rowptr) {
  int g = blockIdx.x * blockDim.x + threadIdx.x;
  if (g < n) rowptr[g] = exsc[g] + bsum[g >> 10];
  if (g == n) rowptr[n] = nETot;
}

// ---- fillcsr: ATOMIC-FREE — pos = rowptr[dst] + rank[i]
__global__ void fillcsr(const int* __restrict__ src_ui, const int* __restrict__ dst_ui,
                        const float* __restrict__ nrm_ui, int nE_ui,
                        const int* __restrict__ src_iu, const int* __restrict__ dst_iu,
                        const float* __restrict__ nrm_iu, int nE_iu,
                        int NU, const int* __restrict__ rowptr,
                        const int* __restrict__ rank, int2* __restrict__ pay) {
  int i = blockIdx.x * blockDim.x + threadIdx.x;
  int stride = gridDim.x * blockDim.x;
  int nTot = nE_ui + nE_iu;
  for (; i < nTot; i += stride) {
    int d, s; float nm;
    if (i < nE_ui) { d = NU + dst_ui[i]; s = src_ui[i]; nm = nrm_ui[i]; }
    else { int k = i - nE_ui; d = dst_iu[k]; s = src_iu[k]; nm = nrm_iu[k]; }
    const int pos = rowptr[d] + rank[i];
    int2 p; p.x = s; p.y = __float_as_int(nm);
    pay[pos] = p;
  }
}

// ---- pullfin v4: quarter-wave rows (16 lanes/row, 4 rows/wave), uint4
//      gathers (16B/lane), 4-deep unroll -> up to 16 outstanding gathers/wave.
// h[r] = A_self[r] + (S-1)*Q[r] - b2 + sum_e norm_e * A_gather[src_e]; lrelu+L2norm.
__global__ __launch_bounds__(256) void pullfin(
    const int* __restrict__ rowptr, const int2* __restrict__ pay,
    const unsigned short* __restrict__ Ac,
    const unsigned short* __restrict__ Au, const unsigned short* __restrict__ Ai,
    const unsigned short* __restrict__ Qc,
    const float* __restrict__ b2,
    float* __restrict__ out, int NU, int ntot) {
  const int lane = threadIdx.x & 63;
  const int h    = lane & 15;          // lane within quarter-wave
  const int q    = lane >> 4;          // quarter 0..3
  float b2v[8];
  {
    float4 lo = *(const float4*)(b2 + h * 8);
    float4 hi = *(const float4*)(b2 + h * 8 + 4);
    b2v[0] = lo.x; b2v[1] = lo.y; b2v[2] = lo.z; b2v[3] = lo.w;
    b2v[4] = hi.x; b2v[5] = hi.y; b2v[6] = hi.z; b2v[7] = hi.w;
  }

  int r = (((blockIdx.x * blockDim.x + threadIdx.x) >> 6) << 2) + q;
  const int rstride = ((gridDim.x * blockDim.x) >> 6) << 2;
  for (; r < ntot; r += rstride) {
    const unsigned short* Ag = (r < NU) ? Ai : Au;
    const int beg = rowptr[r], end = rowptr[r + 1];
    float a[8] = {0.f, 0.f, 0.f, 0.f, 0.f, 0.f, 0.f, 0.f};
    float sn = 0.f;
    int e = beg;
    for (; e + 3 < end; e += 4) {
      int2 p0 = pay[e], p1 = pay[e + 1], p2 = pay[e + 2], p3 = pay[e + 3];
      uint4 g0 = *(const uint4*)(Ag + (size_t)p0.x * DDIM + h * 8);
      uint4 g1 = *(const uint4*)(Ag + (size_t)p1.x * DDIM + h * 8);
      uint4 g2 = *(const uint4*)(Ag + (size_t)p2.x * DDIM + h * 8);
      uint4 g3 = *(const uint4*)(Ag + (size_t)p3.x * DDIM + h * 8);
      float n0 = __int_as_float(p0.y), n1 = __int_as_float(p1.y);
      float n2 = __int_as_float(p2.y), n3 = __int_as_float(p3.y);
      sn += (n0 + n1) + (n2 + n3);
      acc8(a, n0, g0);
      acc8(a, n1, g1);
      acc8(a, n2, g2);
      acc8(a, n3, g3);
    }
    for (; e < end; ++e) {
      int2 p0 = pay[e];
      uint4 g0 = *(const uint4*)(Ag + (size_t)p0.x * DDIM + h * 8);
      float n0 = __int_as_float(p0.y);
      sn += n0;
      acc8(a, n0, g0);
    }

    uint4 av = *(const uint4*)(Ac + (size_t)r * DDIM + h * 8);
    uint4 qv = *(const uint4*)(Qc + (size_t)r * DDIM + h * 8);
    const float s1 = sn - 1.0f;
    float v[8];
    v[0] = bf2f((unsigned short)(av.x & 0xffffu)) + s1 * bf2f((unsigned short)(qv.x & 0xffffu)) - b2v[0] + a[0];
    v[1] = bf2f((unsigned short)(av.x >> 16))     + s1 * bf2f((unsigned short)(qv.x >> 16))     - b2v[1] + a[1];
    v[2] = bf2f((unsigned short)(av.y & 0xffffu)) + s1 * bf2f((unsigned short)(qv.y & 0xffffu)) - b2v[2] + a[2];
    v[3] = bf2f((unsigned short)(av.y >> 16))     + s1 * bf2f((unsigned short)(qv.y >> 16))     - b2v[3] + a[3];
    v[4] = bf2f((unsigned short)(av.z & 0xffffu)) + s1 * bf2f((unsigned short)(qv.z & 0xffffu)) - b2v[4] + a[4];
    v[5] = bf2f((unsigned short)(av.z >> 16))     + s1 * bf2f((unsigned short)(qv.z >> 16))     - b2v[5] + a[5];
    v[6] = bf2f((unsigned short)(av.w & 0xffffu)) + s1 * bf2f((unsigned short)(qv.w & 0xffffu)) - b2v[6] + a[6];
    v[7] = bf2f((unsigned short)(av.w >> 16))     + s1 * bf2f((unsigned short)(qv.w >> 16))     - b2v[7] + a[7];

    float sq = 0.f;
#pragma unroll
    for (int j = 0; j < 8; ++j) {
      v[j] = v[j] > 0.f ? v[j] : 0.2f * v[j];
      sq += v[j] * v[j];
    }
#pragma unroll
    for (int off = 8; off; off >>= 1) sq += __shfl_xor(sq, off);  // within 16-lane quarter
    float sc = 1.0f / fmaxf(sqrtf(sq), 1e-12f);
    f32x4 lo, hi;
    lo.x = v[0] * sc; lo.y = v[1] * sc; lo.z = v[2] * sc; lo.w = v[3] * sc;
    hi.x = v[4] * sc; hi.y = v[5] * sc; hi.z = v[6] * sc; hi.w = v[7] * sc;
    float* o = out + (size_t)r * DDIM + h * 8;
    __builtin_nontemporal_store(lo, (f32x4*)o);
    __builtin_nontemporal_store(hi, (f32x4*)(o + 4));
  }
}

extern "C" void kernel_launch(void* const* d_in, const int* in_sizes, int n_in,
                              void* d_out, int out_size, void* d_ws, size_t ws_size,
                              hipStream_t stream) {
  const float* x_user  = (const float*)d_in[0];
  const float* x_item  = (const float*)d_in[1];
  const float* W1      = (const float*)d_in[2];
  const float* b1      = (const float*)d_in[3];
  const float* W2      = (const float*)d_in[4];
  const float* b2      = (const float*)d_in[5];
  const int*   src_ui  = (const int*)d_in[6];
  const int*   dst_ui  = (const int*)d_in[7];
  const float* norm_ui = (const float*)d_in[8];
  const int*   src_iu  = (const int*)d_in[9];
  const int*   dst_iu  = (const int*)d_in[10];
  const float* norm_iu = (const float*)d_in[11];

  const int NUr   = in_sizes[0] / DDIM;   // 100000
  const int NIr   = in_sizes[1] / DDIM;   // 50000
  const int nE_ui = in_sizes[6];          // 300000
  const int nE_iu = in_sizes[9];
  const int nTot  = NUr + NIr;
  const int nETot = nE_ui + nE_iu;

  float* out = (float*)d_out;             // rows: [h_user (NUr); h_item (NIr)]

  char* ws = (char*)d_ws;
  size_t off = 0;
  auto alloc = [&](size_t bytes) { char* p = ws + off; off += (bytes + 15) & ~(size_t)15; return p; };
  unsigned short* wb  = (unsigned short*)alloc(32768 * 2);
  unsigned short* Ac  = (unsigned short*)alloc((size_t)nTot * DDIM * 2);  // [Au; Ai]
  unsigned short* Qc  = (unsigned short*)alloc((size_t)nTot * DDIM * 2);  // [Qu; Qi]
  int*   deg          = (int*)alloc((size_t)nTot * 4);
  int*   exsc         = (int*)alloc((size_t)nTot * 4);
  int*   bsum         = (int*)alloc(256 * 4);
  int*   rowptr       = (int*)alloc(((size_t)nTot + 1) * 4);
  int*   rank         = (int*)alloc((size_t)nETot * 4);
  int2*  pay          = (int2*)alloc((size_t)nETot * 8);

  unsigned short* Au = Ac;
  unsigned short* Ai = Ac + (size_t)NUr * DDIM;
  unsigned short* Qu = Qc;
  unsigned short* Qi = Qc + (size_t)NUr * DDIM;

  (void)hipMemsetAsync(deg, 0, (size_t)nTot * 4, stream);

  const int gU = (NUr + 63) / 64;         // 1563
  const int gI = (NIr + 63) / 64;         // 782
  const int nTiles = gU + gI;             // 2345

  convW<<<128, 256, 0, stream>>>(W1, W2, wb);
  proj<<<512, 512, 0, stream>>>(x_user, NUr, gU, x_item, NIr, nTiles,
                                wb, b1, b2, Au, Qu, Ai, Qi,
                                dst_ui, nE_ui, dst_iu, nE_iu, deg, rank);

  const int nb = (nTot + 1023) / 1024;    // 147
  scan1<<<nb, 1024, 0, stream>>>(deg, nTot, exsc, bsum);
  scan2<<<1, 256, 0, stream>>>(bsum, nb);
  scan3<<<(nTot + 256) / 256, 256, 0, stream>>>(exsc, bsum, nTot, nETot, rowptr);
  fillcsr<<<2048, 256, 0, stream>>>(src_ui, dst_ui, norm_ui, nE_ui,
                                    src_iu, dst_iu, norm_iu, nE_iu, NUr, rowptr, rank, pay);
  pullfin<<<9376, 256, 0, stream>>>(rowptr, pay, Ac, Au, Ai, Qc, b2, out, NUr, nTot);
}